// Round 4
// baseline (425.708 us; speedup 1.0000x reference)
//
#include <hip/hip_runtime.h>

// Batched Kalman filter: B batches, N=8 state, M=4 measurement, fp32.
//
// R1: no launch bounds -> 64 VGPR cap -> ~1.7 GB spill traffic, 645 us.
// R2: __launch_bounds__(256,2): allocator still chose 128 VGPR, spilled ~400MB, 304 us.
// R3: waves_per_eu(2,2) ignored by allocator (VGPR stuck at 128), ~125 MB spill, 173 us.
// R4: restructure instead of fighting the allocator: 8 LANES PER BATCH
//     (lane = matrix row), cross-row terms via __shfl(width=8).
//     Per-lane live set ~70 floats -> no spill at any cap; and all bulk
//     loads/stores become linear in global thread id t:
//       F/P/Q rows at base + t*8, P_new at base + t*8, K at base + t*4,
//       x at base + t  -> perfectly coalesced float4 traffic.
// Outputs flat-concatenated: x_new[B*8], P_new[B*64], K[B*32].

#define EPS 1e-6f

__global__ __launch_bounds__(256, 4)
void kf_kernel(const float* __restrict__ x_est,
               const float* __restrict__ P_est,
               const float* __restrict__ Fin,
               const float* __restrict__ Qin,
               const float* __restrict__ zin,
               const float* __restrict__ Hin,
               const float* __restrict__ Rin,
               float* __restrict__ out, int B) {
    int t = blockIdx.x * blockDim.x + threadIdx.x;  // global lane-task id
    int l = t & 7;                                  // row index within batch
    int b = t >> 3;                                 // batch index
    if (b >= B) return;
    size_t sb = (size_t)b;

    // ---- load F row l, P row l (addr = base + t*8: linear, coalesced) ----
    float Fr[8], Pr[8];
    {
        const float4* p = reinterpret_cast<const float4*>(Fin) + (size_t)t * 2;
        float4 a = p[0], c = p[1];
        Fr[0]=a.x; Fr[1]=a.y; Fr[2]=a.z; Fr[3]=a.w; Fr[4]=c.x; Fr[5]=c.y; Fr[6]=c.z; Fr[7]=c.w;
    }
    {
        const float4* p = reinterpret_cast<const float4*>(P_est) + (size_t)t * 2;
        float4 a = p[0], c = p[1];
        Pr[0]=a.x; Pr[1]=a.y; Pr[2]=a.z; Pr[3]=a.w; Pr[4]=c.x; Pr[5]=c.y; Pr[6]=c.z; Pr[7]=c.w;
    }
    float xl = x_est[t];  // x[l] of this batch

    // ---- xp = F[l] . x  (broadcast x elements) ----
    float xp = 0.f;
#pragma unroll
    for (int j = 0; j < 8; ++j) xp += Fr[j] * __shfl(xl, j, 8);

    // ---- T[l][j] = sum_k F[l][k] * P[k][j]  (P row k lives in lane k) ----
    float T[8] = {0.f, 0.f, 0.f, 0.f, 0.f, 0.f, 0.f, 0.f};
#pragma unroll
    for (int k = 0; k < 8; ++k) {
        float f = Fr[k];
#pragma unroll
        for (int j = 0; j < 8; ++j) T[j] += f * __shfl(Pr[j], k, 8);
    }

    // ---- Pp[l][j] = sum_k T[l][k] * F[j][k] + Q[l][j] ----
    float Pp[8];
    {
        const float4* p = reinterpret_cast<const float4*>(Qin) + (size_t)t * 2;
        float4 a = p[0], c = p[1];
        float q[8] = {a.x, a.y, a.z, a.w, c.x, c.y, c.z, c.w};
#pragma unroll
        for (int j = 0; j < 8; ++j) {
            float s = q[j];
#pragma unroll
            for (int k = 0; k < 8; ++k) s += T[k] * __shfl(Fr[k], j, 8);
            Pp[j] = s;
        }
    }

    // ---- load H row, R row, z (lanes 0..3 only; zero elsewhere) ----
    float Hr[8] = {0.f, 0.f, 0.f, 0.f, 0.f, 0.f, 0.f, 0.f};
    float Rr[4] = {0.f, 0.f, 0.f, 0.f};
    float zl = 0.f;
    if (l < 4) {
        const float4* h = reinterpret_cast<const float4*>(Hin + sb * 32 + l * 8);
        float4 a = h[0], c = h[1];
        Hr[0]=a.x; Hr[1]=a.y; Hr[2]=a.z; Hr[3]=a.w; Hr[4]=c.x; Hr[5]=c.y; Hr[6]=c.z; Hr[7]=c.w;
        float4 r = *reinterpret_cast<const float4*>(Rin + sb * 16 + l * 4);
        Rr[0]=r.x; Rr[1]=r.y; Rr[2]=r.z; Rr[3]=r.w;
        zl = zin[sb * 4 + l];
    }

    // ---- HP[l][j] = sum_k H[l][k] * Pp[k][j]  (valid in lanes 0..3, 0 elsewhere) ----
    float HP[8] = {0.f, 0.f, 0.f, 0.f, 0.f, 0.f, 0.f, 0.f};
#pragma unroll
    for (int k = 0; k < 8; ++k) {
        float h = Hr[k];
#pragma unroll
        for (int j = 0; j < 8; ++j) HP[j] += h * __shfl(Pp[j], k, 8);
    }

    // ---- S[l][b] = R[l][b] + eps*(l==b) + sum_k HP[l][k] * H[b][k] ----
    float Sr[4];
#pragma unroll
    for (int bc = 0; bc < 4; ++bc) {
        float s = Rr[bc] + ((bc == l) ? EPS : 0.f);
#pragma unroll
        for (int k = 0; k < 8; ++k) s += HP[k] * __shfl(Hr[k], bc, 8);
        Sr[bc] = s;
    }

    // ---- y[l] = z[l] - H[l] . xp  (lanes 0..3) ----
    float yl = zl;
#pragma unroll
    for (int k = 0; k < 8; ++k) yl -= Hr[k] * __shfl(xp, k, 8);

    // ---- gather full S into every lane (16 shuffles) ----
    float S[16];
#pragma unroll
    for (int a = 0; a < 4; ++a)
#pragma unroll
        for (int bc = 0; bc < 4; ++bc) S[a * 4 + bc] = __shfl(Sr[bc], a, 8);

    // ---- Sinv via adjugate (computed redundantly in every lane) ----
    float inv[16];
    inv[0]  =  S[5]*S[10]*S[15] - S[5]*S[11]*S[14] - S[9]*S[6]*S[15] + S[9]*S[7]*S[14] + S[13]*S[6]*S[11] - S[13]*S[7]*S[10];
    inv[4]  = -S[4]*S[10]*S[15] + S[4]*S[11]*S[14] + S[8]*S[6]*S[15] - S[8]*S[7]*S[14] - S[12]*S[6]*S[11] + S[12]*S[7]*S[10];
    inv[8]  =  S[4]*S[9]*S[15]  - S[4]*S[11]*S[13] - S[8]*S[5]*S[15] + S[8]*S[7]*S[13] + S[12]*S[5]*S[11] - S[12]*S[7]*S[9];
    inv[12] = -S[4]*S[9]*S[14]  + S[4]*S[10]*S[13] + S[8]*S[5]*S[14] - S[8]*S[6]*S[13] - S[12]*S[5]*S[10] + S[12]*S[6]*S[9];
    inv[1]  = -S[1]*S[10]*S[15] + S[1]*S[11]*S[14] + S[9]*S[2]*S[15] - S[9]*S[3]*S[14] - S[13]*S[2]*S[11] + S[13]*S[3]*S[10];
    inv[5]  =  S[0]*S[10]*S[15] - S[0]*S[11]*S[14] - S[8]*S[2]*S[15] + S[8]*S[3]*S[14] + S[12]*S[2]*S[11] - S[12]*S[3]*S[10];
    inv[9]  = -S[0]*S[9]*S[15]  + S[0]*S[11]*S[13] + S[8]*S[1]*S[15] - S[8]*S[3]*S[13] - S[12]*S[1]*S[11] + S[12]*S[3]*S[9];
    inv[13] =  S[0]*S[9]*S[14]  - S[0]*S[10]*S[13] - S[8]*S[1]*S[14] + S[8]*S[2]*S[13] + S[12]*S[1]*S[10] - S[12]*S[2]*S[9];
    inv[2]  =  S[1]*S[6]*S[15]  - S[1]*S[7]*S[14]  - S[5]*S[2]*S[15] + S[5]*S[3]*S[14] + S[13]*S[2]*S[7]  - S[13]*S[3]*S[6];
    inv[6]  = -S[0]*S[6]*S[15]  + S[0]*S[7]*S[14]  + S[4]*S[2]*S[15] - S[4]*S[3]*S[14] - S[12]*S[2]*S[7]  + S[12]*S[3]*S[6];
    inv[10] =  S[0]*S[5]*S[15]  - S[0]*S[7]*S[13]  - S[4]*S[1]*S[15] + S[4]*S[3]*S[13] + S[12]*S[1]*S[7]  - S[12]*S[3]*S[5];
    inv[14] = -S[0]*S[5]*S[14]  + S[0]*S[6]*S[13]  + S[4]*S[1]*S[14] - S[4]*S[2]*S[13] - S[12]*S[1]*S[6]  + S[12]*S[2]*S[5];
    inv[3]  = -S[1]*S[6]*S[11]  + S[1]*S[7]*S[10]  + S[5]*S[2]*S[11] - S[5]*S[3]*S[10] - S[9]*S[2]*S[7]   + S[9]*S[3]*S[6];
    inv[7]  =  S[0]*S[6]*S[11]  - S[0]*S[7]*S[10]  - S[4]*S[2]*S[11] + S[4]*S[3]*S[10] + S[8]*S[2]*S[7]   - S[8]*S[3]*S[6];
    inv[11] = -S[0]*S[5]*S[11]  + S[0]*S[7]*S[9]   + S[4]*S[1]*S[11] - S[4]*S[3]*S[9]  - S[8]*S[1]*S[7]   + S[8]*S[3]*S[5];
    inv[15] =  S[0]*S[5]*S[10]  - S[0]*S[6]*S[9]   - S[4]*S[1]*S[10] + S[4]*S[2]*S[9]  + S[8]*S[1]*S[6]   - S[8]*S[2]*S[5];
    float det = S[0]*inv[0] + S[1]*inv[4] + S[2]*inv[8] + S[3]*inv[12];
    float rdet = 1.0f / det;
#pragma unroll
    for (int i = 0; i < 16; ++i) inv[i] *= rdet;

    // ---- hp[a] = HP[a][l]  (column extract via broadcast + select) ----
    float hp[4];
#pragma unroll
    for (int a = 0; a < 4; ++a) {
        float v = 0.f;
#pragma unroll
        for (int j = 0; j < 8; ++j) {
            float u = __shfl(HP[j], a, 8);
            v = (l == j) ? u : v;
        }
        hp[a] = v;
    }

    // ---- K[l][b] = sum_a HP[a][l] * Sinv[a][b]   (Pp H^T = (HP)^T, Pp symmetric) ----
    float K[4];
#pragma unroll
    for (int bc = 0; bc < 4; ++bc) {
        float s = 0.f;
#pragma unroll
        for (int a = 0; a < 4; ++a) s += hp[a] * inv[a * 4 + bc];
        K[bc] = s;
    }

    // ---- x_new[l] = xp + sum_b K[l][b] * y[b] ----
    float xn = xp;
#pragma unroll
    for (int bc = 0; bc < 4; ++bc) xn += K[bc] * __shfl(yl, bc, 8);
    out[t] = xn;  // out + sb*8 + l == out + t

    // ---- P_new[l][j] = Pp[l][j] - sum_a K[l][a] * HP[a][j] ----
    float Pn[8];
#pragma unroll
    for (int j = 0; j < 8; ++j) Pn[j] = Pp[j];
#pragma unroll
    for (int a = 0; a < 4; ++a) {
        float ka = K[a];
#pragma unroll
        for (int j = 0; j < 8; ++j) Pn[j] -= ka * __shfl(HP[j], a, 8);
    }

    size_t Bz = (size_t)B;
    {
        float4* po = reinterpret_cast<float4*>(out + Bz * 8) + (size_t)t * 2;
        po[0] = make_float4(Pn[0], Pn[1], Pn[2], Pn[3]);
        po[1] = make_float4(Pn[4], Pn[5], Pn[6], Pn[7]);
    }
    {
        float4* ko = reinterpret_cast<float4*>(out + Bz * 72) + (size_t)t;
        *ko = make_float4(K[0], K[1], K[2], K[3]);
    }
}

extern "C" void kernel_launch(void* const* d_in, const int* in_sizes, int n_in,
                              void* d_out, int out_size, void* d_ws, size_t ws_size,
                              hipStream_t stream) {
    const float* x_est = (const float*)d_in[0];
    const float* P_est = (const float*)d_in[1];
    const float* F     = (const float*)d_in[2];
    const float* Q     = (const float*)d_in[3];
    const float* z     = (const float*)d_in[4];
    const float* H     = (const float*)d_in[5];
    const float* R     = (const float*)d_in[6];
    float* out = (float*)d_out;
    int B = in_sizes[0] / 8;
    int threads_total = B * 8;
    int block = 256;
    int grid = (threads_total + block - 1) / block;
    kf_kernel<<<grid, block, 0, stream>>>(x_est, P_est, F, Q, z, H, R, out, B);
}